// Round 5
// baseline (507.926 us; speedup 1.0000x reference)
//
#include <hip/hip_runtime.h>
#include <math.h>

#define NPOS 4096   // H*W
#define NB   4      // batch
#define NROW (NB * NPOS)
#define LOG2E 1.44269504088896f

typedef _Float16 f16;
typedef f16 f16x4 __attribute__((ext_vector_type(4)));
typedef f16 f16x8 __attribute__((ext_vector_type(8)));
typedef float f32x4 __attribute__((ext_vector_type(4)));

// ---------------------------------------------------------------------------
// Kernel 1: QKV projection as MFMA GEMM, 16-position tiles -> 1024 blocks
// (4 blocks/CU, latency-hiding). Per block: 16 pos x 192 outputs, K=64.
// Each wave computes 3 of the 12 output tiles with a shared A-fragment.
// q pre-scaled by log2(e); pos bias folded into k; v stored [c][n].
// ---------------------------------------------------------------------------
#define LDW 72

__global__ __launch_bounds__(256) void qkv_proj(
    const float* __restrict__ x,
    const float* __restrict__ Wq, const float* __restrict__ bq,
    const float* __restrict__ Wk, const float* __restrict__ bk,
    const float* __restrict__ Wv, const float* __restrict__ bv,
    const float* __restrict__ rel_h, const float* __restrict__ rel_w,
    f16* __restrict__ qh, f16* __restrict__ kh, f16* __restrict__ vh)
{
    __shared__ __align__(16) f16 Ws[192 * LDW];  // [o_all][c]
    __shared__ __align__(16) f16 Xs[16 * LDW];   // [n_local][c]
    __shared__ __align__(16) f16 Vs[64 * 20];    // v transpose buffer [c][n_local]

    const int tid = threadIdx.x;
    const int b   = blockIdx.x >> 8;           // 256 tiles per batch
    const int n0  = (blockIdx.x & 255) << 4;   // 16-position tile

    // stage W (3 x 64 x 64 fp32 -> f16 row-major)
    #pragma unroll
    for (int k = 0; k < 12; ++k) {
        int idx  = tid + k * 256;
        int orow = idx >> 4;
        int cseg = (idx & 15) << 2;
        int mat  = orow >> 6;
        int o    = orow & 63;
        const float* wsrc = (mat == 0) ? Wq : ((mat == 1) ? Wk : Wv);
        float4 v = *(const float4*)(wsrc + o * 64 + cseg);
        f16x4 h; h[0] = (f16)v.x; h[1] = (f16)v.y; h[2] = (f16)v.z; h[3] = (f16)v.w;
        *(f16x4*)(&Ws[orow * LDW + cseg]) = h;
    }
    // stage X transposed: 16 pos x 64 ch = 256 float4 reads
    {
        int c  = tid >> 2;
        int ns = (tid & 3) << 2;
        float4 v = *(const float4*)(x + ((size_t)(b * 64 + c)) * NPOS + n0 + ns);
        Xs[(ns + 0) * LDW + c] = (f16)v.x;
        Xs[(ns + 1) * LDW + c] = (f16)v.y;
        Xs[(ns + 2) * LDW + c] = (f16)v.z;
        Xs[(ns + 3) * LDW + c] = (f16)v.w;
    }
    __syncthreads();

    const int wave = tid >> 6;
    const int lane = tid & 63;
    const int quad = lane >> 4;
    const int l16  = lane & 15;

    const f16x8 a0 = *(const f16x8*)(&Xs[l16 * LDW + quad * 8]);
    const f16x8 a1 = *(const f16x8*)(&Xs[l16 * LDW + 32 + quad * 8]);

    f32x4 acc[3];
    const int t0 = wave * 3;
    #pragma unroll
    for (int i = 0; i < 3; ++i) {
        int t = t0 + i;
        f32x4 c0 = {0, 0, 0, 0};
        f16x8 b0 = *(const f16x8*)(&Ws[(t * 16 + l16) * LDW + quad * 8]);
        f16x8 b1 = *(const f16x8*)(&Ws[(t * 16 + l16) * LDW + 32 + quad * 8]);
        c0 = __builtin_amdgcn_mfma_f32_16x16x32_f16(a0, b0, c0, 0, 0, 0);
        c0 = __builtin_amdgcn_mfma_f32_16x16x32_f16(a1, b1, c0, 0, 0, 0);
        acc[i] = c0;
    }

    #pragma unroll
    for (int i = 0; i < 3; ++i) {
        int t = t0 + i;
        if (t < 4) {                       // q tiles
            int o = t * 16 + l16;
            float bb = bq[o];
            #pragma unroll
            for (int r = 0; r < 4; ++r) {
                size_t n = (size_t)b * NPOS + n0 + quad * 4 + r;
                qh[n * 64 + o] = (f16)((acc[i][r] + bb) * LOG2E);
            }
        } else if (t < 8) {                // k tiles (+ positional bias)
            int o = (t - 4) * 16 + l16;
            int h = n0 >> 6;               // 16-tiles never straddle a row of 64
            int wbase = n0 & 63;
            float bb = bk[o] + rel_h[o * 64 + h];
            #pragma unroll
            for (int r = 0; r < 4; ++r) {
                size_t n = (size_t)b * NPOS + n0 + quad * 4 + r;
                kh[n * 64 + o] = (f16)(acc[i][r] + bb + rel_w[o * 64 + wbase + quad * 4 + r]);
            }
        } else {                           // v tiles -> LDS transpose
            int o = (t - 8) * 16 + l16;
            float bb = bv[o];
            #pragma unroll
            for (int r = 0; r < 4; ++r)
                Vs[o * 20 + quad * 4 + r] = (f16)(acc[i][r] + bb);
        }
    }
    __syncthreads();
    {
        int c  = tid >> 2;
        int ns = (tid & 3) << 2;
        f16x4 vv = *(const f16x4*)(&Vs[c * 20 + ns]);
        *(f16x4*)(vh + ((size_t)(b * 64 + c)) * NPOS + n0 + ns) = vv;
    }
}

// ---------------------------------------------------------------------------
// Kernel 2: flash attention (S^T = K Q^T), 128-m iterations, split-K with
// fused last-block combine (device-scope atomic counter + threadfence).
//   S^T C-layout: row=m=quad*4+r, col=n=l16 -> in-lane softmax + 2 shuffles;
//   P registers ARE the 16x16x16 A-fragment; conditional O-rescale (skipped
//   once the running max stabilizes — wave-uniform branch via __any).
// LDS: Ks 128x72 + Vt 64x136 = 35840 B -> 4 blocks/CU.
// ---------------------------------------------------------------------------
#define LDK 72
#define LDV 136

__global__ __launch_bounds__(256, 4) void attn(
    const f16* __restrict__ qh, const f16* __restrict__ kh,
    const f16* __restrict__ vh,
    f16* __restrict__ Op, float* __restrict__ Mp, float* __restrict__ Lp,
    int* __restrict__ cnt, float* __restrict__ out,
    int split, int mchunk)
{
    __shared__ __align__(16) f16 Ks[128 * LDK];  // K-tile [m_local][c]
    __shared__ __align__(16) f16 Vt[64 * LDV];   // V-tile [c][m_local]
    __shared__ int lastFlag;

    const int tid  = threadIdx.x;
    const int wave = tid >> 6;
    const int lane = tid & 63;
    const int quad = lane >> 4;
    const int l16  = lane & 15;
    const int s    = blockIdx.x % split;
    const int tile = blockIdx.x / split;
    const int b    = tile >> 6;
    const int n0   = (tile & 63) << 6;

    // Q as B-operand: B[quad*8+j][l16] = Q[n=l16][c=quad*8+j]
    const f16* qbase = qh + ((size_t)b * NPOS + n0 + wave * 16 + l16) * 64;
    const f16x8 bq0 = *(const f16x8*)(qbase + quad * 8);
    const f16x8 bq1 = *(const f16x8*)(qbase + 32 + quad * 8);

    f32x4 O[4] = {{0,0,0,0},{0,0,0,0},{0,0,0,0},{0,0,0,0}};
    float m_i = -1e30f, l_i = 0.f;

    const int krow = tid >> 1;          // 0..127
    const int kseg = (tid & 1) * 32;    // 0 / 32
    const int vrow = tid >> 2;          // 0..63
    const int vseg = (tid & 3) * 32;    // 0..96
    const f16* kb = kh + (size_t)b * NPOS * 64;
    const f16* vb = vh + (size_t)b * 64 * NPOS;

    const int m_begin = s * mchunk;
    for (int m0 = m_begin; m0 < m_begin + mchunk; m0 += 128) {
        const f16* ks = kb + (size_t)(m0 + krow) * 64 + kseg;
        #pragma unroll
        for (int j = 0; j < 4; ++j)
            *(f16x8*)(&Ks[krow * LDK + kseg + 8 * j]) = *(const f16x8*)(ks + 8 * j);
        const f16* vs = vb + (size_t)vrow * NPOS + m0 + vseg;
        #pragma unroll
        for (int j = 0; j < 4; ++j)
            *(f16x8*)(&Vt[vrow * LDV + vseg + 8 * j]) = *(const f16x8*)(vs + 8 * j);
        __syncthreads();

        // S^T = K Q^T over 8 m-subtiles of 16
        f32x4 S[8];
        #pragma unroll
        for (int t = 0; t < 8; ++t) {
            f32x4 acc = {0, 0, 0, 0};
            f16x8 ak0 = *(const f16x8*)(&Ks[(t * 16 + l16) * LDK + quad * 8]);
            f16x8 ak1 = *(const f16x8*)(&Ks[(t * 16 + l16) * LDK + 32 + quad * 8]);
            acc = __builtin_amdgcn_mfma_f32_16x16x32_f16(ak0, bq0, acc, 0, 0, 0);
            acc = __builtin_amdgcn_mfma_f32_16x16x32_f16(ak1, bq1, acc, 0, 0, 0);
            S[t] = acc;
        }

        // column max (n = l16): 31 in-lane fmax + 2 shuffles
        float mx = S[0][0];
        #pragma unroll
        for (int t = 0; t < 8; ++t)
            #pragma unroll
            for (int r = 0; r < 4; ++r) mx = fmaxf(mx, S[t][r]);
        mx = fmaxf(mx, __shfl_xor(mx, 16));
        mx = fmaxf(mx, __shfl_xor(mx, 32));

        // conditional rescale: skipped once max has stabilized (wave-uniform)
        if (__any(mx > m_i)) {
            float mnew  = fmaxf(m_i, mx);
            float alpha = __builtin_amdgcn_exp2f(m_i - mnew);
            m_i = mnew;
            l_i *= alpha;
            #pragma unroll
            for (int r = 0; r < 4; ++r) {
                float av = __shfl(alpha, quad * 20 + r);  // lane owning column quad*4+r
                O[0][r] *= av; O[1][r] *= av; O[2][r] *= av; O[3][r] *= av;
            }
        }

        // exp2 + pack A-fragments + row-sum
        float rs = 0.f;
        f16x4 pa[8];
        #pragma unroll
        for (int t = 0; t < 8; ++t) {
            f16x4 a;
            #pragma unroll
            for (int r = 0; r < 4; ++r) {
                float e = __builtin_amdgcn_exp2f(S[t][r] - m_i);
                rs += e;
                a[r] = (f16)e;
            }
            pa[t] = a;
        }
        rs += __shfl_xor(rs, 16);
        rs += __shfl_xor(rs, 32);
        l_i += rs;

        // O += P V  (4 c-tiles x 8 m-steps of 16x16x16)
        #pragma unroll
        for (int u = 0; u < 4; ++u) {
            #pragma unroll
            for (int t = 0; t < 8; ++t) {
                f16x4 bf = *(const f16x4*)(&Vt[(u * 16 + l16) * LDV + t * 16 + quad * 4]);
                O[u] = __builtin_amdgcn_mfma_f32_16x16x16f16(pa[t], bf, O[u], 0, 0, 0);
            }
        }
        __syncthreads();
    }

    // ---- write partials ----
    #pragma unroll
    for (int r = 0; r < 4; ++r) {
        float lr  = __shfl(l_i, quad * 20 + r);
        float inv = 1.f / lr;
        size_t row = (size_t)b * NPOS + n0 + wave * 16 + quad * 4 + r;
        #pragma unroll
        for (int u = 0; u < 4; ++u)
            Op[((size_t)s * NROW + row) * 64 + u * 16 + l16] = (f16)(O[u][r] * inv);
    }
    if (lane < 16) {
        size_t row = (size_t)b * NPOS + n0 + wave * 16 + l16;
        Mp[(size_t)s * NROW + row] = m_i;
        Lp[(size_t)s * NROW + row] = l_i;
    }

    // ---- last-block-done combine ----
    __threadfence();                       // release partials to device scope
    __syncthreads();
    if (tid == 0) {
        int old = atomicAdd(&cnt[tile], 1);
        lastFlag = (old == split - 1);
    }
    __syncthreads();
    if (!lastFlag) return;
    __threadfence();                       // acquire other blocks' partials

    float* Ot = (float*)Ks;                // reuse LDS: 64 x 68 floats
    {
        int nl = tid >> 2;
        int cs = (tid & 3) << 4;
        size_t row = (size_t)b * NPOS + n0 + nl;

        float M = -1e30f;
        for (int s2 = 0; s2 < split; ++s2)
            M = fmaxf(M, Mp[(size_t)s2 * NROW + row]);

        float L = 0.f;
        float val[16];
        #pragma unroll
        for (int j = 0; j < 16; ++j) val[j] = 0.f;
        for (int s2 = 0; s2 < split; ++s2) {
            float w = Lp[(size_t)s2 * NROW + row] *
                      __builtin_amdgcn_exp2f(Mp[(size_t)s2 * NROW + row] - M);
            L += w;
            const f16* op = Op + ((size_t)s2 * NROW + row) * 64 + cs;
            f16x8 o0 = *(const f16x8*)(op);
            f16x8 o1 = *(const f16x8*)(op + 8);
            #pragma unroll
            for (int j = 0; j < 8; ++j) {
                val[j]     += w * (float)o0[j];
                val[8 + j] += w * (float)o1[j];
            }
        }
        float invL = 1.f / L;
        #pragma unroll
        for (int k = 0; k < 4; ++k) {
            float4 v4 = { val[4*k] * invL, val[4*k+1] * invL,
                          val[4*k+2] * invL, val[4*k+3] * invL };
            *(float4*)(&Ot[nl * 68 + cs + 4 * k]) = v4;
        }
    }
    __syncthreads();
    {
        int c  = tid >> 2;
        int ns = (tid & 3) << 4;
        float* dst = out + ((size_t)(b * 64 + c)) * NPOS + n0 + ns;
        #pragma unroll
        for (int k = 0; k < 4; ++k) {
            float4 v4 = { Ot[(ns + 4*k + 0) * 68 + c], Ot[(ns + 4*k + 1) * 68 + c],
                          Ot[(ns + 4*k + 2) * 68 + c], Ot[(ns + 4*k + 3) * 68 + c] };
            *(float4*)(&dst[4 * k]) = v4;
        }
    }
}

// ---------------------------------------------------------------------------
extern "C" void kernel_launch(void* const* d_in, const int* in_sizes, int n_in,
                              void* d_out, int out_size, void* d_ws, size_t ws_size,
                              hipStream_t stream) {
    const float* x     = (const float*)d_in[0];
    const float* Wq    = (const float*)d_in[1];
    const float* bq    = (const float*)d_in[2];
    const float* Wk    = (const float*)d_in[3];
    const float* bk    = (const float*)d_in[4];
    const float* Wv    = (const float*)d_in[5];
    const float* bv    = (const float*)d_in[6];
    const float* rel_h = (const float*)d_in[7];
    const float* rel_w = (const float*)d_in[8];
    float* out = (float*)d_out;

    const size_t qkv_elems = (size_t)NROW * 64;
    int split = 8;
    {
        size_t need = 3 * qkv_elems * sizeof(f16)
                    + (size_t)split * NROW * 64 * sizeof(f16)
                    + 2 * (size_t)split * NROW * sizeof(float)
                    + 256 * sizeof(int);
        if (ws_size < need) split = 4;     // deterministic wrt ws_size
    }
    const int mchunk = NPOS / split;       // multiple of 128

    f16* qh = (f16*)d_ws;
    f16* kh = qh + qkv_elems;
    f16* vh = kh + qkv_elems;
    f16* Op = vh + qkv_elems;
    float* Mp = (float*)(Op + (size_t)split * NROW * 64);
    float* Lp = Mp + (size_t)split * NROW;
    int*  cnt = (int*)(Lp + (size_t)split * NROW);

    hipMemsetAsync(cnt, 0, 256 * sizeof(int), stream);
    qkv_proj<<<NB * (NPOS / 16), 256, 0, stream>>>(x, Wq, bq, Wk, bk, Wv, bv,
                                                   rel_h, rel_w, qh, kh, vh);
    attn<<<NB * (NPOS / 64) * split, 256, 0, stream>>>(qh, kh, vh, Op, Mp, Lp,
                                                       cnt, out, split, mchunk);
}

// Round 6
// 127.369 us; speedup vs baseline: 3.9878x; 3.9878x over previous
//
#include <hip/hip_runtime.h>
#include <math.h>

#define NPOS 4096   // H*W
#define NB   4      // batch
#define NROW (NB * NPOS)
#define LOG2E 1.44269504088896f

typedef _Float16 f16;
typedef f16 f16x4 __attribute__((ext_vector_type(4)));
typedef f16 f16x8 __attribute__((ext_vector_type(8)));
typedef float f32x4 __attribute__((ext_vector_type(4)));

// ---------------------------------------------------------------------------
// Kernel 1: QKV projection as MFMA GEMM, 16-position tiles -> 1024 blocks
// (4 blocks/CU). Per block: 16 pos x 192 outputs, K=64. Each wave computes
// 3 of the 12 output tiles with a shared A-fragment.
// q pre-scaled by log2(e); pos bias folded into k; v stored [c][n].
// ---------------------------------------------------------------------------
#define LDW 72

__global__ __launch_bounds__(256) void qkv_proj(
    const float* __restrict__ x,
    const float* __restrict__ Wq, const float* __restrict__ bq,
    const float* __restrict__ Wk, const float* __restrict__ bk,
    const float* __restrict__ Wv, const float* __restrict__ bv,
    const float* __restrict__ rel_h, const float* __restrict__ rel_w,
    f16* __restrict__ qh, f16* __restrict__ kh, f16* __restrict__ vh)
{
    __shared__ __align__(16) f16 Ws[192 * LDW];  // [o_all][c]
    __shared__ __align__(16) f16 Xs[16 * LDW];   // [n_local][c]
    __shared__ __align__(16) f16 Vs[64 * 20];    // v transpose buffer [c][n_local]

    const int tid = threadIdx.x;
    const int b   = blockIdx.x >> 8;           // 256 tiles per batch
    const int n0  = (blockIdx.x & 255) << 4;   // 16-position tile

    #pragma unroll
    for (int k = 0; k < 12; ++k) {
        int idx  = tid + k * 256;
        int orow = idx >> 4;
        int cseg = (idx & 15) << 2;
        int mat  = orow >> 6;
        int o    = orow & 63;
        const float* wsrc = (mat == 0) ? Wq : ((mat == 1) ? Wk : Wv);
        float4 v = *(const float4*)(wsrc + o * 64 + cseg);
        f16x4 h; h[0] = (f16)v.x; h[1] = (f16)v.y; h[2] = (f16)v.z; h[3] = (f16)v.w;
        *(f16x4*)(&Ws[orow * LDW + cseg]) = h;
    }
    {
        int c  = tid >> 2;
        int ns = (tid & 3) << 2;
        float4 v = *(const float4*)(x + ((size_t)(b * 64 + c)) * NPOS + n0 + ns);
        Xs[(ns + 0) * LDW + c] = (f16)v.x;
        Xs[(ns + 1) * LDW + c] = (f16)v.y;
        Xs[(ns + 2) * LDW + c] = (f16)v.z;
        Xs[(ns + 3) * LDW + c] = (f16)v.w;
    }
    __syncthreads();

    const int wave = tid >> 6;
    const int lane = tid & 63;
    const int quad = lane >> 4;
    const int l16  = lane & 15;

    const f16x8 a0 = *(const f16x8*)(&Xs[l16 * LDW + quad * 8]);
    const f16x8 a1 = *(const f16x8*)(&Xs[l16 * LDW + 32 + quad * 8]);

    f32x4 acc[3];
    const int t0 = wave * 3;
    #pragma unroll
    for (int i = 0; i < 3; ++i) {
        int t = t0 + i;
        f32x4 c0 = {0, 0, 0, 0};
        f16x8 b0 = *(const f16x8*)(&Ws[(t * 16 + l16) * LDW + quad * 8]);
        f16x8 b1 = *(const f16x8*)(&Ws[(t * 16 + l16) * LDW + 32 + quad * 8]);
        c0 = __builtin_amdgcn_mfma_f32_16x16x32_f16(a0, b0, c0, 0, 0, 0);
        c0 = __builtin_amdgcn_mfma_f32_16x16x32_f16(a1, b1, c0, 0, 0, 0);
        acc[i] = c0;
    }

    #pragma unroll
    for (int i = 0; i < 3; ++i) {
        int t = t0 + i;
        if (t < 4) {                       // q tiles
            int o = t * 16 + l16;
            float bb = bq[o];
            #pragma unroll
            for (int r = 0; r < 4; ++r) {
                size_t n = (size_t)b * NPOS + n0 + quad * 4 + r;
                qh[n * 64 + o] = (f16)((acc[i][r] + bb) * LOG2E);
            }
        } else if (t < 8) {                // k tiles (+ positional bias)
            int o = (t - 4) * 16 + l16;
            int h = n0 >> 6;               // 16-tiles never straddle a row of 64
            int wbase = n0 & 63;
            float bb = bk[o] + rel_h[o * 64 + h];
            #pragma unroll
            for (int r = 0; r < 4; ++r) {
                size_t n = (size_t)b * NPOS + n0 + quad * 4 + r;
                kh[n * 64 + o] = (f16)(acc[i][r] + bb + rel_w[o * 64 + wbase + quad * 4 + r]);
            }
        } else {                           // v tiles -> LDS transpose
            int o = (t - 8) * 16 + l16;
            float bb = bv[o];
            #pragma unroll
            for (int r = 0; r < 4; ++r)
                Vs[o * 20 + quad * 4 + r] = (f16)(acc[i][r] + bb);
        }
    }
    __syncthreads();
    {
        int c  = tid >> 2;
        int ns = (tid & 3) << 2;
        f16x4 vv = *(const f16x4*)(&Vs[c * 20 + ns]);
        *(f16x4*)(vh + ((size_t)(b * 64 + c)) * NPOS + n0 + ns) = vv;
    }
}

// ---------------------------------------------------------------------------
// Kernel 2: flash attention via S^T = K Q^T (round-4 known-good structure:
// 64-m tiles, LDS 18432 B -> 8 blocks/CU, split-K, partials to workspace).
// Round-6 addition: conditional O-rescale, skipped via wave-uniform __any
// once the running max has stabilized. NO global fences/atomics (r5 lesson:
// device-scope fences serialize L2 writebacks across 2048 blocks).
// ---------------------------------------------------------------------------
#define LDP 72

__global__ __launch_bounds__(256, 8) void attn(
    const f16* __restrict__ qh, const f16* __restrict__ kh,
    const f16* __restrict__ vh,
    f16* __restrict__ Op, float* __restrict__ Mp, float* __restrict__ Lp,
    int split, int mchunk)
{
    __shared__ __align__(16) f16 Ks[64 * LDP];   // K-tile [m_local][c]
    __shared__ __align__(16) f16 Vt[64 * LDP];   // V-tile [c][m_local]

    const int tid  = threadIdx.x;
    const int wave = tid >> 6;
    const int lane = tid & 63;
    const int quad = lane >> 4;
    const int l16  = lane & 15;
    const int s    = blockIdx.x % split;
    const int tile = blockIdx.x / split;
    const int b    = tile >> 6;
    const int n0   = (tile & 63) << 6;

    // Q as B-operand: B[quad*8+j][l16] = Q[n=l16][c=quad*8+j]
    const f16* qbase = qh + ((size_t)b * NPOS + n0 + wave * 16 + l16) * 64;
    const f16x8 bq0 = *(const f16x8*)(qbase + quad * 8);
    const f16x8 bq1 = *(const f16x8*)(qbase + 32 + quad * 8);

    f32x4 O[4] = {{0,0,0,0},{0,0,0,0},{0,0,0,0},{0,0,0,0}};
    float m_i = -1e30f, l_i = 0.f;

    const int srow = tid >> 2;
    const int sseg = (tid & 3) * 16;
    const f16* kb = kh + (size_t)b * NPOS * 64;
    const f16* vb = vh + (size_t)b * 64 * NPOS;

    const int m_begin = s * mchunk;
    for (int m0 = m_begin; m0 < m_begin + mchunk; m0 += 64) {
        const f16* ksrc = kb + (size_t)(m0 + srow) * 64 + sseg;
        *(f16x8*)(&Ks[srow * LDP + sseg])     = *(const f16x8*)(ksrc);
        *(f16x8*)(&Ks[srow * LDP + sseg + 8]) = *(const f16x8*)(ksrc + 8);
        const f16* vsrc = vb + (size_t)srow * NPOS + m0 + sseg;
        *(f16x8*)(&Vt[srow * LDP + sseg])     = *(const f16x8*)(vsrc);
        *(f16x8*)(&Vt[srow * LDP + sseg + 8]) = *(const f16x8*)(vsrc + 8);
        __syncthreads();

        // S^T = K Q^T  (4 m-tiles of 16; K-dim 64 = 2 chained MFMAs)
        f32x4 S[4];
        #pragma unroll
        for (int t = 0; t < 4; ++t) {
            f32x4 acc = {0, 0, 0, 0};
            f16x8 ak0 = *(const f16x8*)(&Ks[(t * 16 + l16) * LDP + quad * 8]);
            f16x8 ak1 = *(const f16x8*)(&Ks[(t * 16 + l16) * LDP + 32 + quad * 8]);
            acc = __builtin_amdgcn_mfma_f32_16x16x32_f16(ak0, bq0, acc, 0, 0, 0);
            acc = __builtin_amdgcn_mfma_f32_16x16x32_f16(ak1, bq1, acc, 0, 0, 0);
            S[t] = acc;
        }

        // column max (n = l16): 15 in-lane fmax + 2 shuffles
        float mx = S[0][0];
        #pragma unroll
        for (int t = 0; t < 4; ++t)
            #pragma unroll
            for (int r = 0; r < 4; ++r) mx = fmaxf(mx, S[t][r]);
        mx = fmaxf(mx, __shfl_xor(mx, 16));
        mx = fmaxf(mx, __shfl_xor(mx, 32));

        // conditional rescale (wave-uniform skip once max is stable)
        if (__any(mx > m_i)) {
            float mnew  = fmaxf(m_i, mx);
            float alpha = __builtin_amdgcn_exp2f(m_i - mnew);
            m_i = mnew;
            l_i *= alpha;
            #pragma unroll
            for (int r = 0; r < 4; ++r) {
                float av = __shfl(alpha, quad * 20 + r);  // lane owning column quad*4+r
                O[0][r] *= av; O[1][r] *= av; O[2][r] *= av; O[3][r] *= av;
            }
        }

        // exp2 + pack A-fragments + row-sum
        float rs = 0.f;
        f16x4 pa[4];
        #pragma unroll
        for (int t = 0; t < 4; ++t) {
            f16x4 a;
            #pragma unroll
            for (int r = 0; r < 4; ++r) {
                float e = __builtin_amdgcn_exp2f(S[t][r] - m_i);
                rs += e;
                a[r] = (f16)e;
            }
            pa[t] = a;
        }
        rs += __shfl_xor(rs, 16);
        rs += __shfl_xor(rs, 32);
        l_i += rs;

        // O += P V  (4 c-tiles x 4 m-steps of 16x16x16)
        #pragma unroll
        for (int u = 0; u < 4; ++u) {
            #pragma unroll
            for (int t = 0; t < 4; ++t) {
                f16x4 bf = *(const f16x4*)(&Vt[(u * 16 + l16) * LDP + t * 16 + quad * 4]);
                O[u] = __builtin_amdgcn_mfma_f32_16x16x16f16(pa[t], bf, O[u], 0, 0, 0);
            }
        }
        __syncthreads();
    }

    // partial epilogue
    #pragma unroll
    for (int r = 0; r < 4; ++r) {
        float lr  = __shfl(l_i, quad * 20 + r);
        float inv = 1.f / lr;
        size_t row = (size_t)b * NPOS + n0 + wave * 16 + quad * 4 + r;
        #pragma unroll
        for (int u = 0; u < 4; ++u)
            Op[((size_t)s * NROW + row) * 64 + u * 16 + l16] = (f16)(O[u][r] * inv);
    }
    if (lane < 16) {
        size_t row = (size_t)b * NPOS + n0 + wave * 16 + l16;
        Mp[(size_t)s * NROW + row] = m_i;
        Lp[(size_t)s * NROW + row] = l_i;
    }
}

// ---------------------------------------------------------------------------
// Kernel 3: combine split partials. grid 1024 (16-row tiles, 4 blocks/CU)
// to get out of the 1-block/CU latency regime. LDS transpose for coalesced
// [c][n] float4 stores.
// ---------------------------------------------------------------------------
__global__ __launch_bounds__(256) void combine(
    const f16* __restrict__ Op, const float* __restrict__ Mp,
    const float* __restrict__ Lp, float* __restrict__ out, int split)
{
    __shared__ float Ot[16 * 68];   // [n_local][c] padded

    const int tid = threadIdx.x;
    const int b   = blockIdx.x >> 8;            // 256 tiles of 16 rows per batch
    const int n0  = (blockIdx.x & 255) << 4;

    {
        int nl = tid >> 4;            // 0..15 row within tile
        int cs = (tid & 15) << 2;     // 4-channel chunk
        size_t row = (size_t)b * NPOS + n0 + nl;

        float M = -1e30f;
        for (int s2 = 0; s2 < split; ++s2)
            M = fmaxf(M, Mp[(size_t)s2 * NROW + row]);

        float L = 0.f;
        float val[4] = {0.f, 0.f, 0.f, 0.f};
        for (int s2 = 0; s2 < split; ++s2) {
            float w = Lp[(size_t)s2 * NROW + row] *
                      __builtin_amdgcn_exp2f(Mp[(size_t)s2 * NROW + row] - M);
            L += w;
            f16x4 o0 = *(const f16x4*)(Op + ((size_t)s2 * NROW + row) * 64 + cs);
            #pragma unroll
            for (int j = 0; j < 4; ++j) val[j] += w * (float)o0[j];
        }
        float invL = 1.f / L;
        float4 v4 = { val[0] * invL, val[1] * invL, val[2] * invL, val[3] * invL };
        *(float4*)(&Ot[nl * 68 + cs]) = v4;
    }
    __syncthreads();
    {
        int c  = tid >> 2;            // 0..63
        int ns = (tid & 3) << 2;      // 0..12
        float4 v4 = { Ot[(ns + 0) * 68 + c], Ot[(ns + 1) * 68 + c],
                      Ot[(ns + 2) * 68 + c], Ot[(ns + 3) * 68 + c] };
        *(float4*)(out + ((size_t)(b * 64 + c)) * NPOS + n0 + ns) = v4;
    }
}

// ---------------------------------------------------------------------------
extern "C" void kernel_launch(void* const* d_in, const int* in_sizes, int n_in,
                              void* d_out, int out_size, void* d_ws, size_t ws_size,
                              hipStream_t stream) {
    const float* x     = (const float*)d_in[0];
    const float* Wq    = (const float*)d_in[1];
    const float* bq    = (const float*)d_in[2];
    const float* Wk    = (const float*)d_in[3];
    const float* bk    = (const float*)d_in[4];
    const float* Wv    = (const float*)d_in[5];
    const float* bv    = (const float*)d_in[6];
    const float* rel_h = (const float*)d_in[7];
    const float* rel_w = (const float*)d_in[8];
    float* out = (float*)d_out;

    const size_t qkv_elems = (size_t)NROW * 64;
    int split = 8;
    {
        size_t need = 3 * qkv_elems * sizeof(f16)
                    + (size_t)split * NROW * 64 * sizeof(f16)
                    + 2 * (size_t)split * NROW * sizeof(float);
        if (ws_size < need) split = 4;     // deterministic wrt ws_size
    }
    const int mchunk = NPOS / split;

    f16* qh = (f16*)d_ws;
    f16* kh = qh + qkv_elems;
    f16* vh = kh + qkv_elems;
    f16* Op = vh + qkv_elems;
    float* Mp = (float*)(Op + (size_t)split * NROW * 64);
    float* Lp = Mp + (size_t)split * NROW;

    qkv_proj<<<NB * (NPOS / 16), 256, 0, stream>>>(x, Wq, bq, Wk, bk, Wv, bv,
                                                   rel_h, rel_w, qh, kh, vh);
    attn<<<NB * (NPOS / 64) * split, 256, 0, stream>>>(qh, kh, vh, Op, Mp, Lp,
                                                       split, mchunk);
    combine<<<NB * (NPOS / 16), 256, 0, stream>>>(Op, Mp, Lp, out, split);
}